// Round 1
// baseline (211.096 us; speedup 1.0000x reference)
//
#include <hip/hip_runtime.h>
#include <hip/hip_bf16.h>

#define N 4096
#define F 256
#define P 5
#define EPSV 1e-8f
#define BK 32
#define LDK 40  // padded LDS leading dim (elements): 80B rows, 16B-aligned, low bank conflict

typedef __attribute__((ext_vector_type(8))) short bf16x8;
typedef __attribute__((ext_vector_type(4))) float f32x4;

__device__ __forceinline__ f32x4 mfma16(bf16x8 a, bf16x8 b, f32x4 c) {
    return __builtin_amdgcn_mfma_f32_16x16x32_bf16(a, b, c, 0, 0, 0);
}

// K0: msg = E @ A, exploiting ~1% sparsity of E via per-row index compaction.
__global__ __launch_bounds__(256) void msg_kernel(const float* __restrict__ E,
                                                  const float* __restrict__ A,
                                                  float* __restrict__ msg) {
    __shared__ int cnt;
    __shared__ int list[1024];
    const int a = blockIdx.x;
    const int t = threadIdx.x;
    if (t == 0) cnt = 0;
    __syncthreads();
    const float* erow = E + (size_t)a * N;
    for (int b = t; b < N; b += 256) {
        if (erow[b] != 0.0f) {
            int pos = atomicAdd(&cnt, 1);
            list[pos] = b;
        }
    }
    __syncthreads();
    const int c = cnt;
    float acc = 0.f;
    for (int j = 0; j < c; ++j) {
        acc += A[(size_t)list[j] * F + t];
    }
    msg[(size_t)a * F + t] = acc;
}

// K1: per-row norms -> alpha/beta per persona; bf16 casts of A and msg; per-persona consts.
__global__ __launch_bounds__(256) void row_kernel(
    const float* __restrict__ A, const float* __restrict__ msg,
    const float* __restrict__ Tt, const float* __restrict__ ee,
    const float* __restrict__ rr, const float* __restrict__ Ww,
    __hip_bfloat16* __restrict__ Abf, __hip_bfloat16* __restrict__ Mbf,
    float* __restrict__ alpha, float* __restrict__ beta, float* __restrict__ cst) {
    const int a = blockIdx.x, t = threadIdx.x;
    const float av = A[(size_t)a * F + t];
    const float mv = msg[(size_t)a * F + t];
    Abf[(size_t)a * F + t] = __float2bfloat16(av);
    Mbf[(size_t)a * F + t] = __float2bfloat16(mv);
    float paa = av * av, pam = av * mv, pmm = mv * mv;
    #pragma unroll
    for (int o = 32; o > 0; o >>= 1) {
        paa += __shfl_down(paa, o);
        pam += __shfl_down(pam, o);
        pmm += __shfl_down(pmm, o);
    }
    __shared__ float s[3][4];
    const int wid = t >> 6;
    if ((t & 63) == 0) { s[0][wid] = paa; s[1][wid] = pam; s[2][wid] = pmm; }
    __syncthreads();
    if (t < P) {
        const float naa = s[0][0] + s[0][1] + s[0][2] + s[0][3];
        const float nam = s[1][0] + s[1][1] + s[1][2] + s[1][3];
        const float nmm = s[2][0] + s[2][1] + s[2][2] + s[2][3];
        const float Ti = Tt[t], ei = ee[t], ri = rr[t], Wi = Ww[t];
        const float wb = (1.f - ri) * Wi;
        const float n2 = ri * ri * naa + 2.f * ri * wb * nam + wb * wb * nmm;
        const float rn = rsqrtf(n2);   // reference has no eps in the norm
        alpha[t * N + a] = ri * rn;
        beta[t * N + a] = wb * rn;
        if (a == 0) {
            // x = e*exp(g*invT) / (e*exp(invT) + EPS)  [max g == 1 analytically]
            const float invT = 1.f / (Ti + EPSV);
            cst[2 * t] = invT * 1.4426950408889634f;          // k1: exponent scale (log2)
            cst[2 * t + 1] = ei / (ei * __expf(invT) + EPSV); // scale
        }
    }
}

// K2: fused 4-Gram MFMA + persona epilogue. 64x64 tile, 4 waves, each wave a 32x32 quadrant.
__global__ __launch_bounds__(256) void gram_kernel(
    const __hip_bfloat16* __restrict__ Abf, const __hip_bfloat16* __restrict__ Mbf,
    const float* __restrict__ alpha, const float* __restrict__ beta,
    const float* __restrict__ cst, const float* __restrict__ persona,
    const int* __restrict__ times, float* __restrict__ out) {
    __shared__ __align__(16) __hip_bfloat16 sAa[64 * LDK];
    __shared__ __align__(16) __hip_bfloat16 sMa[64 * LDK];
    __shared__ __align__(16) __hip_bfloat16 sAb[64 * LDK];
    __shared__ __align__(16) __hip_bfloat16 sMb[64 * LDK];

    const int t = threadIdx.x;
    const int lane = t & 63;
    const int wid = t >> 6;
    const int wr = wid >> 1, wc = wid & 1;
    const int by = blockIdx.x >> 6, bx = blockIdx.x & 63;
    const int row0 = by << 6, col0 = bx << 6;

    f32x4 acc[4][2][2];  // [gram: AA,AM,MA,MM][m][n]
    #pragma unroll
    for (int g = 0; g < 4; ++g)
        #pragma unroll
        for (int m = 0; m < 2; ++m)
            #pragma unroll
            for (int n = 0; n < 2; ++n) acc[g][m][n] = (f32x4){0.f, 0.f, 0.f, 0.f};

    const int srow = t >> 2;          // 0..63
    const int sch = (t & 3) << 3;     // element offset 0,8,16,24

    for (int ks = 0; ks < F; ks += BK) {
        const uint4 va = *(const uint4*)(Abf + (size_t)(row0 + srow) * F + ks + sch);
        const uint4 vma = *(const uint4*)(Mbf + (size_t)(row0 + srow) * F + ks + sch);
        const uint4 vb = *(const uint4*)(Abf + (size_t)(col0 + srow) * F + ks + sch);
        const uint4 vmb = *(const uint4*)(Mbf + (size_t)(col0 + srow) * F + ks + sch);
        __syncthreads();
        *(uint4*)(sAa + srow * LDK + sch) = va;
        *(uint4*)(sMa + srow * LDK + sch) = vma;
        *(uint4*)(sAb + srow * LDK + sch) = vb;
        *(uint4*)(sMb + srow * LDK + sch) = vmb;
        __syncthreads();

        const int frow = lane & 15;
        const int fk = (lane >> 4) << 3;
        bf16x8 aA[2], aM[2], bA[2], bM[2];
        #pragma unroll
        for (int m = 0; m < 2; ++m) {
            aA[m] = *(const bf16x8*)(sAa + (wr * 32 + m * 16 + frow) * LDK + fk);
            aM[m] = *(const bf16x8*)(sMa + (wr * 32 + m * 16 + frow) * LDK + fk);
        }
        #pragma unroll
        for (int n = 0; n < 2; ++n) {
            bA[n] = *(const bf16x8*)(sAb + (wc * 32 + n * 16 + frow) * LDK + fk);
            bM[n] = *(const bf16x8*)(sMb + (wc * 32 + n * 16 + frow) * LDK + fk);
        }
        #pragma unroll
        for (int m = 0; m < 2; ++m)
            #pragma unroll
            for (int n = 0; n < 2; ++n) {
                acc[0][m][n] = mfma16(aA[m], bA[n], acc[0][m][n]);
                acc[1][m][n] = mfma16(aA[m], bM[n], acc[1][m][n]);
                acc[2][m][n] = mfma16(aM[m], bA[n], acc[2][m][n]);
                acc[3][m][n] = mfma16(aM[m], bM[n], acc[3][m][n]);
            }
    }

    // Epilogue: g = (aa*A + ba*M)_row . (ab*A + bb*M)_col scaled cosines -> x -> tanh -> gated acc
    const int tim = *times;
    const float* pp = persona + (size_t)tim * (size_t)N * P;
    float oacc[2][2][4];
    #pragma unroll
    for (int m = 0; m < 2; ++m)
        #pragma unroll
        for (int n = 0; n < 2; ++n)
            #pragma unroll
            for (int j = 0; j < 4; ++j) oacc[m][n][j] = 0.f;

    #pragma unroll
    for (int i = 0; i < P; ++i) {
        const float k1 = cst[2 * i], sc = cst[2 * i + 1];
        float abn[2], bbn[2], pbn[2];
        #pragma unroll
        for (int n = 0; n < 2; ++n) {
            const int gc = col0 + wc * 32 + n * 16 + (lane & 15);
            abn[n] = alpha[i * N + gc];
            bbn[n] = beta[i * N + gc];
            pbn[n] = pp[(size_t)gc * P + i];
        }
        #pragma unroll
        for (int m = 0; m < 2; ++m) {
            #pragma unroll
            for (int j = 0; j < 4; ++j) {
                const int gr = row0 + wr * 32 + m * 16 + ((lane >> 4) << 2) + j;
                const float aa = alpha[i * N + gr];
                const float ba = beta[i * N + gr];
                const float pr = pp[(size_t)gr * P + i] + (i == 0 ? 1.f : 0.f);
                #pragma unroll
                for (int n = 0; n < 2; ++n) {
                    const float g = aa * (abn[n] * acc[0][m][n][j] + bbn[n] * acc[1][m][n][j])
                                  + ba * (abn[n] * acc[2][m][n][j] + bbn[n] * acc[3][m][n][j]);
                    const float x = sc * exp2f(g * k1);
                    const float u = exp2f(-2.8853900817779268f * x);  // exp(-2x)
                    const float th = (1.f - u) / (1.f + u);           // tanh(x)
                    oacc[m][n][j] += th * pbn[n] * pr;
                }
            }
        }
    }
    #pragma unroll
    for (int m = 0; m < 2; ++m)
        #pragma unroll
        for (int j = 0; j < 4; ++j) {
            const int gr = row0 + wr * 32 + m * 16 + ((lane >> 4) << 2) + j;
            #pragma unroll
            for (int n = 0; n < 2; ++n) {
                const int gc = col0 + wc * 32 + n * 16 + (lane & 15);
                out[(size_t)gr * N + gc] = oacc[m][n][j];
            }
        }
}

extern "C" void kernel_launch(void* const* d_in, const int* in_sizes, int n_in,
                              void* d_out, int out_size, void* d_ws, size_t ws_size,
                              hipStream_t stream) {
    const float* A = (const float*)d_in[0];
    const float* E = (const float*)d_in[1];
    const float* persona = (const float*)d_in[2];
    const float* T = (const float*)d_in[3];
    const float* e = (const float*)d_in[4];
    const float* r = (const float*)d_in[5];
    const float* W = (const float*)d_in[6];
    const int* times = (const int*)d_in[7];
    float* out = (float*)d_out;

    char* ws = (char*)d_ws;
    float* msg = (float*)ws;                                      // 4 MB
    __hip_bfloat16* Abf = (__hip_bfloat16*)(ws + (4 << 20));      // 2 MB
    __hip_bfloat16* Mbf = (__hip_bfloat16*)(ws + (6 << 20));      // 2 MB
    float* alpha = (float*)(ws + (8 << 20));                      // 80 KB
    float* beta = (float*)(ws + (8 << 20) + P * N * 4);           // 80 KB
    float* cst = (float*)(ws + (8 << 20) + 2 * P * N * 4);        // 40 B

    msg_kernel<<<N, 256, 0, stream>>>(E, A, msg);
    row_kernel<<<N, 256, 0, stream>>>(A, msg, T, e, r, W, Abf, Mbf, alpha, beta, cst);
    gram_kernel<<<64 * 64, 256, 0, stream>>>(Abf, Mbf, alpha, beta, cst, persona, times, out);
}

// Round 2
// 121.392 us; speedup vs baseline: 1.7390x; 1.7390x over previous
//
#include <hip/hip_runtime.h>
#include <hip/hip_bf16.h>

#define N 4096
#define F 256
#define P 5
#define EPSV 1e-8f
#define BK 32
#define NSTEP (F / BK)  // 8

typedef __attribute__((ext_vector_type(8))) short bf16x8;
typedef __attribute__((ext_vector_type(4))) float f32x4;

__device__ __forceinline__ f32x4 mfma16(bf16x8 a, bf16x8 b, f32x4 c) {
    return __builtin_amdgcn_mfma_f32_16x16x32_bf16(a, b, c, 0, 0, 0);
}

__device__ __forceinline__ void gload16(const __hip_bfloat16* src, const char* ldsdst) {
    __builtin_amdgcn_global_load_lds(
        (const __attribute__((address_space(1))) void*)src,
        (__attribute__((address_space(3))) void*)ldsdst, 16, 0, 0);
}

// K0: msg = E @ A, exploiting ~1% sparsity of E via per-row index compaction.
__global__ __launch_bounds__(256) void msg_kernel(const float* __restrict__ E,
                                                  const float* __restrict__ A,
                                                  float* __restrict__ msg) {
    __shared__ int cnt;
    __shared__ int list[1024];
    const int a = blockIdx.x;
    const int t = threadIdx.x;
    if (t == 0) cnt = 0;
    __syncthreads();
    const float* erow = E + (size_t)a * N;
    for (int b = t; b < N; b += 256) {
        if (erow[b] != 0.0f) {
            int pos = atomicAdd(&cnt, 1);
            list[pos] = b;
        }
    }
    __syncthreads();
    const int c = cnt;
    float acc = 0.f;
    for (int j = 0; j < c; ++j) {
        acc += A[(size_t)list[j] * F + t];
    }
    msg[(size_t)a * F + t] = acc;
}

// K1: per-row norms -> alpha/beta per persona; bf16 casts of A and msg; per-persona consts.
__global__ __launch_bounds__(256) void row_kernel(
    const float* __restrict__ A, const float* __restrict__ msg,
    const float* __restrict__ Tt, const float* __restrict__ ee,
    const float* __restrict__ rr, const float* __restrict__ Ww,
    __hip_bfloat16* __restrict__ Abf, __hip_bfloat16* __restrict__ Mbf,
    float* __restrict__ alpha, float* __restrict__ beta, float* __restrict__ cst) {
    const int a = blockIdx.x, t = threadIdx.x;
    const float av = A[(size_t)a * F + t];
    const float mv = msg[(size_t)a * F + t];
    Abf[(size_t)a * F + t] = __float2bfloat16(av);
    Mbf[(size_t)a * F + t] = __float2bfloat16(mv);
    float paa = av * av, pam = av * mv, pmm = mv * mv;
    #pragma unroll
    for (int o = 32; o > 0; o >>= 1) {
        paa += __shfl_down(paa, o);
        pam += __shfl_down(pam, o);
        pmm += __shfl_down(pmm, o);
    }
    __shared__ float s[3][4];
    const int wid = t >> 6;
    if ((t & 63) == 0) { s[0][wid] = paa; s[1][wid] = pam; s[2][wid] = pmm; }
    __syncthreads();
    if (t < P) {
        const float naa = s[0][0] + s[0][1] + s[0][2] + s[0][3];
        const float nam = s[1][0] + s[1][1] + s[1][2] + s[1][3];
        const float nmm = s[2][0] + s[2][1] + s[2][2] + s[2][3];
        const float Ti = Tt[t], ei = ee[t], ri = rr[t], Wi = Ww[t];
        const float wb = (1.f - ri) * Wi;
        const float n2 = ri * ri * naa + 2.f * ri * wb * nam + wb * wb * nmm;
        const float rn = rsqrtf(n2);
        alpha[t * N + a] = ri * rn;
        beta[t * N + a] = wb * rn;
        if (a == 0) {
            // x = e*exp(g*invT) / (e*exp(invT) + EPS)  [max g == 1 analytically]
            const float invT = 1.f / (Ti + EPSV);
            cst[2 * t] = invT * 1.4426950408889634f;          // exponent scale (log2)
            cst[2 * t + 1] = ei / (ei * __expf(invT) + EPSV); // post-exp scale
        }
    }
}

// K2: fused 4-Gram MFMA + dual-tile persona epilogue over the upper triangle.
// 64x64 tile, 4 waves (2x2), global_load_lds double-buffered staging, swizzled LDS.
__global__ __launch_bounds__(256) void gram_kernel(
    const __hip_bfloat16* __restrict__ Abf, const __hip_bfloat16* __restrict__ Mbf,
    const float* __restrict__ alpha, const float* __restrict__ beta,
    const float* __restrict__ cst, const float* __restrict__ persona,
    const int* __restrict__ times, float* __restrict__ out) {
    // 2 buffers x 4 panels (rowA,rowM,colA,colM) x [64][32] bf16 = 32 KB; reused for transpose.
    __shared__ __align__(16) char smem[32768];

    const int t = threadIdx.x;
    const int lane = t & 63;
    const int w = t >> 6;
    const int wr = w >> 1, wc = w & 1;

    // triangle decode: bid -> (by <= bx)
    int bid = blockIdx.x;
    int bx = (int)((sqrtf(8.f * (float)bid + 1.f) - 1.f) * 0.5f);
    while ((bx + 1) * (bx + 2) / 2 <= bid) ++bx;
    while (bx * (bx + 1) / 2 > bid) --bx;
    const int by = bid - bx * (bx + 1) / 2;
    const int row0 = by << 6, col0 = bx << 6;

    // staging geometry: wave w stages rows [w*16, w*16+16) of each panel, 16B/lane,
    // source column pre-swizzled (involution: slot ^ ((row>>1)&3)) so LDS stays linear.
    const int srow = lane >> 2;                       // row within wave strip
    const int sslot = (lane & 3) ^ ((lane >> 3) & 3); // swizzled 16B slot
    const size_t rbase = (size_t)row0 * F;
    const size_t cbase = (size_t)col0 * F;
    const size_t soff = (size_t)(w * 16 + srow) * F + (sslot << 3);

    #define STAGE(b, ks)  do {                                            \
        const char* lb = smem + (b) * 16384 + w * 1024;                   \
        gload16(Abf + rbase + soff + (ks), lb);                           \
        gload16(Mbf + rbase + soff + (ks), lb + 4096);                    \
        gload16(Abf + cbase + soff + (ks), lb + 8192);                    \
        gload16(Mbf + cbase + soff + (ks), lb + 12288);                   \
    } while (0)

    // fragment-read geometry (matching swizzle)
    const int frow = lane & 15;
    const int rdslot = ((lane >> 4) ^ ((frow >> 1) & 3)) << 4;

    f32x4 acc[4][2][2];
    #pragma unroll
    for (int g = 0; g < 4; ++g)
        #pragma unroll
        for (int m = 0; m < 2; ++m)
            #pragma unroll
            for (int n = 0; n < 2; ++n) acc[g][m][n] = (f32x4){0.f, 0.f, 0.f, 0.f};

    STAGE(0, 0);
    __syncthreads();
    for (int s = 0; s < NSTEP; ++s) {
        const int b = s & 1;
        if (s + 1 < NSTEP) STAGE(b ^ 1, (s + 1) * BK);
        const char* base = smem + b * 16384;
        bf16x8 aA[2], aM[2], bA[2], bM[2];
        #pragma unroll
        for (int m = 0; m < 2; ++m) {
            const int ro = (wr * 32 + m * 16 + frow) * 64 + rdslot;
            aA[m] = *(const bf16x8*)(base + ro);
            aM[m] = *(const bf16x8*)(base + 4096 + ro);
        }
        #pragma unroll
        for (int n = 0; n < 2; ++n) {
            const int co = (wc * 32 + n * 16 + frow) * 64 + rdslot;
            bA[n] = *(const bf16x8*)(base + 8192 + co);
            bM[n] = *(const bf16x8*)(base + 12288 + co);
        }
        #pragma unroll
        for (int m = 0; m < 2; ++m)
            #pragma unroll
            for (int n = 0; n < 2; ++n) {
                acc[0][m][n] = mfma16(aA[m], bA[n], acc[0][m][n]);
                acc[1][m][n] = mfma16(aA[m], bM[n], acc[1][m][n]);
                acc[2][m][n] = mfma16(aM[m], bA[n], acc[2][m][n]);
                acc[3][m][n] = mfma16(aM[m], bM[n], acc[3][m][n]);
            }
        __syncthreads();
    }

    // Epilogue: g symmetric; out(r,c) = sum th*p(c)*(p(r)+d), out(c,r) = sum th*p(r)*(p(c)+d)
    const int tim = *times;
    const float* pp = persona + (size_t)tim * (size_t)N * P;
    const int jr = (lane >> 4) << 2;
    float o1[2][2][4], o2[2][2][4];
    #pragma unroll
    for (int m = 0; m < 2; ++m)
        #pragma unroll
        for (int n = 0; n < 2; ++n)
            #pragma unroll
            for (int j = 0; j < 4; ++j) { o1[m][n][j] = 0.f; o2[m][n][j] = 0.f; }

    #pragma unroll
    for (int i = 0; i < P; ++i) {
        const float k1 = cst[2 * i], sc = cst[2 * i + 1];
        float can[2], cbn[2], pc0[2], pc1[2];
        #pragma unroll
        for (int n = 0; n < 2; ++n) {
            const int gc = col0 + wc * 32 + n * 16 + (lane & 15);
            can[n] = alpha[i * N + gc];
            cbn[n] = beta[i * N + gc];
            pc0[n] = pp[(size_t)gc * P + i];
            pc1[n] = pc0[n] + (i == 0 ? 1.f : 0.f);
        }
        #pragma unroll
        for (int m = 0; m < 2; ++m) {
            #pragma unroll
            for (int j = 0; j < 4; ++j) {
                const int gr = row0 + wr * 32 + m * 16 + jr + j;
                const float aa = alpha[i * N + gr];
                const float ba = beta[i * N + gr];
                const float pr0 = pp[(size_t)gr * P + i];
                const float pr1 = pr0 + (i == 0 ? 1.f : 0.f);
                #pragma unroll
                for (int n = 0; n < 2; ++n) {
                    const float h0 = aa * acc[0][m][n][j] + ba * acc[2][m][n][j];
                    const float h1 = aa * acc[1][m][n][j] + ba * acc[3][m][n][j];
                    const float g = h0 * can[n] + h1 * cbn[n];
                    const float x = sc * exp2f(g * k1);
                    const float e2 = exp2f(x * 2.8853900817779268f);  // exp(2x)
                    const float th = 1.f - 2.f * __builtin_amdgcn_rcpf(e2 + 1.f);
                    o1[m][n][j] = fmaf(th * pc0[n], pr1, o1[m][n][j]);
                    o2[m][n][j] = fmaf(th * pr0, pc1[n], o2[m][n][j]);
                }
            }
        }
    }

    // tile1 (row0, col0): direct coalesced stores
    #pragma unroll
    for (int m = 0; m < 2; ++m)
        #pragma unroll
        for (int j = 0; j < 4; ++j) {
            const int gr = row0 + wr * 32 + m * 16 + jr + j;
            #pragma unroll
            for (int n = 0; n < 2; ++n) {
                const int gc = col0 + wc * 32 + n * 16 + (lane & 15);
                out[(size_t)gr * N + gc] = o1[m][n][j];
            }
        }

    // tile2 (col0, row0): transpose through LDS (XOR-swizzled f32 [64][64]), then float4 stores
    if (by != bx) {
        float* tb = (float*)smem;  // main loop done; last loop barrier guarantees reads finished
        #pragma unroll
        for (int m = 0; m < 2; ++m)
            #pragma unroll
            for (int n = 0; n < 2; ++n) {
                const int lc = wc * 32 + n * 16 + (lane & 15);
                #pragma unroll
                for (int j = 0; j < 4; ++j) {
                    const int lr = wr * 32 + m * 16 + jr + j;
                    tb[lc * 64 + (lr ^ ((lc & 15) << 2))] = o2[m][n][j];
                }
            }
        __syncthreads();
        const int trow = t >> 2;
        const int tc4 = (t & 3) << 2;
        #pragma unroll
        for (int k = 0; k < 4; ++k) {
            const int col = (tc4 + k * 16) ^ ((trow & 15) << 2);
            const float4 v = *(const float4*)&tb[trow * 64 + col];
            *(float4*)&out[(size_t)(col0 + trow) * N + row0 + tc4 + k * 16] = v;
        }
    }
    #undef STAGE
}

extern "C" void kernel_launch(void* const* d_in, const int* in_sizes, int n_in,
                              void* d_out, int out_size, void* d_ws, size_t ws_size,
                              hipStream_t stream) {
    const float* A = (const float*)d_in[0];
    const float* E = (const float*)d_in[1];
    const float* persona = (const float*)d_in[2];
    const float* T = (const float*)d_in[3];
    const float* e = (const float*)d_in[4];
    const float* r = (const float*)d_in[5];
    const float* W = (const float*)d_in[6];
    const int* times = (const int*)d_in[7];
    float* out = (float*)d_out;

    char* ws = (char*)d_ws;
    float* msg = (float*)ws;                                      // 4 MB
    __hip_bfloat16* Abf = (__hip_bfloat16*)(ws + (4 << 20));      // 2 MB
    __hip_bfloat16* Mbf = (__hip_bfloat16*)(ws + (6 << 20));      // 2 MB
    float* alpha = (float*)(ws + (8 << 20));                      // 80 KB
    float* beta = (float*)(ws + (8 << 20) + P * N * 4);           // 80 KB
    float* cst = (float*)(ws + (8 << 20) + 2 * P * N * 4);        // 40 B

    msg_kernel<<<N, 256, 0, stream>>>(E, A, msg);
    row_kernel<<<N, 256, 0, stream>>>(A, msg, T, e, r, W, Abf, Mbf, alpha, beta, cst);
    const int ntri = 64 * 65 / 2;  // 2080 upper-triangle tiles
    gram_kernel<<<ntri, 256, 0, stream>>>(Abf, Mbf, alpha, beta, cst, persona, times, out);
}